// Round 4
// baseline (966.416 us; speedup 1.0000x reference)
//
#include <hip/hip_runtime.h>
#include <math.h>

// Problem constants (from reference)
#define NN 100000          // nodes
#define LF 48              // features per node
#define NE 1600000         // edges
#define EDIMS 17           // edge_attr dim
#define MASKW 3125         // NN/32 bitmask words
#define CAP_E 16384        // per-level edge-list capacity (expected ~5k max)
#define MAXLOC 12288       // active-node capacity (expected ~4.9k)
#define NWAVE_IT 1024      // it-kernel waves (256 blocks x 4 waves); ownership modulus

static_assert((CAP_E & (CAP_E - 1)) == 0, "CAP_E pow2");
static_assert((NWAVE_IT & (NWAVE_IT - 1)) == 0, "NWAVE_IT pow2");

__device__ __forceinline__ float gelu_f(float x) {
    // jax.nn.gelu(approximate=False)
    return 0.5f * x * (1.0f + erff(x * 0.7071067811865475f));
}
__device__ __forceinline__ float sigm_f(float x) {
    return 1.0f / (1.0f + expf(-x));
}

// Per-edge loop-invariant gate scalar, lane-parallel across one wave:
//   w0 = gelu(relu(gelu(ea@W1+b1)@W2+b2)@Wg+bg)@Ww + bw
// Every lane returns w0 (broadcast via full reduce + shfl).
__device__ __forceinline__ float mlp_w0(
    const float* __restrict__ ea, int lane,
    const float* __restrict__ W1, const float* __restrict__ b1,
    const float* __restrict__ W2, const float* __restrict__ b2,
    const float* __restrict__ Wg, const float* __restrict__ bg,
    const float* __restrict__ Ww, const float* __restrict__ bw)
{
    float ea_l = (lane < EDIMS) ? ea[lane] : 0.f;
    float acc1 = (lane < 48) ? b1[lane] : 0.f;
    #pragma unroll
    for (int k = 0; k < EDIMS; ++k) {
        float eak = __shfl(ea_l, k, 64);
        if (lane < 48) acc1 += eak * W1[k * 48 + lane];
    }
    float h1 = (lane < 48) ? gelu_f(acc1) : 0.f;
    float acc2 = (lane < 48) ? b2[lane] : 0.f;
    #pragma unroll 8
    for (int k = 0; k < 48; ++k) {
        float hk = __shfl(h1, k, 64);
        if (lane < 48) acc2 += hk * W2[k * 48 + lane];
    }
    float h2 = fmaxf(acc2, 0.f);
    float acc3 = (lane < 48) ? bg[lane] : 0.f;
    #pragma unroll 8
    for (int k = 0; k < 48; ++k) {
        float hk = __shfl(h2, k, 64);
        if (lane < 48) acc3 += hk * Wg[k * 48 + lane];
    }
    float part = (lane < 48) ? gelu_f(acc3) * Ww[lane] : 0.f;
    #pragma unroll
    for (int o = 32; o > 0; o >>= 1) part += __shfl_down(part, o, 64);
    float w0 = part + bw[0];
    return __shfl(w0, 0, 64);
}

// One BFS level. dst test: d in (MinA|MinB) (or d==0 when MinA==null).
// Selected edges recorded as (src_global, dloc, e, 0). New src nodes first-touch
// a loc via dedupe on Mout (Mout holds only THIS level's new nodes).
__global__ void __launch_bounds__(256) bfs_kernel(
    const int* __restrict__ src, const int* __restrict__ dst,
    const unsigned* __restrict__ MinA, const unsigned* __restrict__ MinB,
    unsigned* __restrict__ Mout, int4* __restrict__ list,
    int* __restrict__ cnt_e, int* __restrict__ cnt_loc,
    int* __restrict__ n2l, int* __restrict__ l2n,
    float* __restrict__ aggz, int aggn)
{
    const int tid = blockIdx.x * 256 + threadIdx.x;
    const int nt = gridDim.x * 256;
    if (aggz) for (int i = tid; i < aggn; i += nt) aggz[i] = 0.f;
    if (!MinA && tid == 0) {
        // seed node 0 (dedupes with any src==0 first-touch via atomicOr)
        unsigned old = atomicOr(&Mout[0], 1u);
        if (!(old & 1u)) {
            int loc = atomicAdd(cnt_loc, 1);
            if (loc < MAXLOC) { n2l[0] = loc; l2n[loc] = 0; }
        }
    }
    const int4* dst4 = (const int4*)dst;
    for (int e4 = tid; e4 < NE / 4; e4 += nt) {
        int4 d4 = dst4[e4];
        int ds_[4] = { d4.x, d4.y, d4.z, d4.w };
        #pragma unroll
        for (int q = 0; q < 4; ++q) {
            int d = ds_[q];
            bool hit;
            if (MinA) {
                unsigned m = MinA[d >> 5];
                if (MinB) m |= MinB[d >> 5];
                hit = (m >> (d & 31)) & 1u;
            } else {
                hit = (d == 0);
            }
            if (hit) {
                int e = e4 * 4 + q;
                int s = src[e];
                int idx = atomicAdd(cnt_e, 1);
                int dloc = MinA ? n2l[d] : 0;   // stable: d assigned in a prior kernel
                if (idx < CAP_E) list[idx] = make_int4(s, dloc, e, 0);
                unsigned sb = 1u << (s & 31);
                unsigned as = 0;
                if (MinA) { as = MinA[s >> 5]; if (MinB) as |= MinB[s >> 5]; }
                if (!(as & sb)) {               // s not assigned in prior levels
                    unsigned old = atomicOr(&Mout[s >> 5], sb);
                    if (!(old & sb)) {          // first touch this level
                        int loc = atomicAdd(cnt_loc, 1);
                        if (loc < MAXLOC) { n2l[s] = loc; l2n[loc] = s; }
                    }
                }
            }
        }
    }
}

// One message-passing iteration: dst-ownership scatter (wave = dloc mod NWAVE_IT,
// exclusive non-atomic accumulate into agg) immediately followed by update of the
// wave's own locs — no sync needed. w0 MLP computed inline per consumed edge.
// Xprev==null => iteration 1 (x_prev/v_prev/meanv recomputed from nodes/valid).
__global__ void __launch_bounds__(256) iter_kernel(
    const float* __restrict__ nodes, const float* __restrict__ valid,
    const float* __restrict__ eattr,
    const float* __restrict__ W1, const float* __restrict__ b1,
    const float* __restrict__ W2, const float* __restrict__ b2,
    const float* __restrict__ Wg, const float* __restrict__ bg,
    const float* __restrict__ Ww, const float* __restrict__ bw,
    const float* __restrict__ Wf, const float* __restrict__ bf,
    const int4* __restrict__ list, const int* __restrict__ cnt_e_p,
    const int* __restrict__ cnt_loc_p,
    const int* __restrict__ n2l, const int* __restrict__ l2n,
    const float* __restrict__ Xprev, const float* __restrict__ Vprev,
    const float* __restrict__ MVprev,
    float* __restrict__ Xc, float* __restrict__ Vc, float* __restrict__ MVc,
    float* __restrict__ agg)
{
    const int wid  = (blockIdx.x * 256 + threadIdx.x) >> 6;
    const int lane = threadIdx.x & 63;
    int c = *cnt_e_p;    if (c > CAP_E) c = CAP_E;
    int nloc = *cnt_loc_p; if (nloc > MAXLOC) nloc = MAXLOC;

    // ---- scatter: scan list in coalesced 64-entry chunks, extract owned edges ----
    for (int base = 0; base < c; base += 64) {
        int4 ent = make_int4(0, 0, 0, 0);
        bool own = false;
        int j = base + lane;
        if (j < c) {
            ent = list[j];
            own = ((unsigned)ent.y < (unsigned)MAXLOC) &&
                  ((ent.y & (NWAVE_IT - 1)) == wid);
        }
        unsigned long long sel = __ballot(own);
        while (sel) {
            int b = __ffsll(sel) - 1;
            sel &= sel - 1;
            int s    = __shfl(ent.x, b, 64);
            int dloc = __shfl(ent.y, b, 64);
            int e    = __shfl(ent.z, b, 64);
            int sloc = n2l[s]; if ((unsigned)sloc >= (unsigned)MAXLOC) sloc = 0;
            float w0 = mlp_w0(eattr + (long)e * EDIMS, lane,
                              W1, b1, W2, b2, Wg, bg, Ww, bw);
            float mv, xj = 0.f;
            if (Xprev) {
                mv = MVprev[sloc];
                if (lane < LF) xj = Xprev[sloc * LF + lane];
            } else {
                float v = 0.f;
                if (lane < LF) {
                    v = valid[(long)s * LF + lane];
                    xj = nodes[(long)s * LF + lane] * v;
                }
                float sv = v;
                #pragma unroll
                for (int o = 32; o > 0; o >>= 1) sv += __shfl_down(sv, o, 64);
                mv = __shfl(sv, 0, 64) * (1.0f / 48.0f);
            }
            float sg = sigm_f(mv * w0);
            if (lane < LF) agg[dloc * LF + lane] += sg * xj;   // exclusive: no atomic
        }
    }

    // ---- update this wave's locs (ownership loc ≡ wid mod NWAVE_IT); re-zero agg ----
    const float wf0 = Wf[0], wf1 = Wf[1], wf2 = Wf[2], bfc = bf[0];
    for (int loc = wid; loc < nloc; loc += NWAVE_IT) {
        int node = l2n[loc];
        float vn = 0.f;
        if (lane < LF) {
            float nh = agg[loc * LF + lane];
            agg[loc * LF + lane] = 0.f;
            float v  = valid[(long)node * LF + lane];
            float x0v = nodes[(long)node * LF + lane] * v;   // original x
            float xo, vp;
            if (Xprev) { xo = Xprev[loc * LF + lane]; vp = Vprev[loc * LF + lane]; }
            else       { xo = x0v;                    vp = v; }
            float nv = 1.0f - vp;
            float m  = sigm_f(nh * wf0 + xo * wf1 + nv * wf2 + bfc);
            float xn = (1.0f - m) * xo + nv * m * nh;
            vn = ((x0v != xn) || (vp > 0.f)) ? 1.0f : 0.0f;
            if (lane == 0) vn = 0.0f;
            Xc[loc * LF + lane] = xn;
            Vc[loc * LF + lane] = vn;
        }
        float sv = vn;
        #pragma unroll
        for (int o = 32; o > 0; o >>= 1) sv += __shfl_down(sv, o, 64);
        if (lane == 0) MVc[loc] = sv * (1.0f / 48.0f);
    }
}

// Final iteration: only node 0 is updated/output. One block; 4 waves split the
// E3 list, partial aggregates reduced through LDS, wave 0 writes out.
__global__ void __launch_bounds__(256) final_kernel(
    const float* __restrict__ eattr,
    const float* __restrict__ W1, const float* __restrict__ b1,
    const float* __restrict__ W2, const float* __restrict__ b2,
    const float* __restrict__ Wg, const float* __restrict__ bg,
    const float* __restrict__ Ww, const float* __restrict__ bw,
    const float* __restrict__ Wf, const float* __restrict__ bf,
    const int4* __restrict__ list, const int* __restrict__ cnt_e_p,
    const int* __restrict__ n2l,
    const float* __restrict__ Xprev, const float* __restrict__ Vprev,
    const float* __restrict__ MVprev, float* __restrict__ out)
{
    __shared__ float part[4][LF];
    const int w = threadIdx.x >> 6;
    const int lane = threadIdx.x & 63;
    int c = *cnt_e_p; if (c > CAP_E) c = CAP_E;
    float acc = 0.f;
    for (int j = w; j < c; j += 4) {
        int4 ent = list[j];
        int sloc = n2l[ent.x]; if ((unsigned)sloc >= (unsigned)MAXLOC) sloc = 0;
        float w0 = mlp_w0(eattr + (long)ent.z * EDIMS, lane,
                          W1, b1, W2, b2, Wg, bg, Ww, bw);
        float sg = sigm_f(MVprev[sloc] * w0);
        if (lane < LF) acc += sg * Xprev[sloc * LF + lane];
    }
    if (lane < LF) part[w][lane] = acc;
    __syncthreads();
    if (w == 0 && lane < LF) {
        float nh = part[0][lane] + part[1][lane] + part[2][lane] + part[3][lane];
        int loc0 = n2l[0]; if ((unsigned)loc0 >= (unsigned)MAXLOC) loc0 = 0;
        float xo = Xprev[loc0 * LF + lane];
        float vp = Vprev[loc0 * LF + lane];
        float nv = 1.0f - vp;
        float m  = sigm_f(nh * Wf[0] + xo * Wf[1] + nv * Wf[2] + bf[0]);
        out[lane] = (1.0f - m) * xo + nv * m * nh;
    }
}

extern "C" void kernel_launch(void* const* d_in, const int* in_sizes, int n_in,
                              void* d_out, int out_size, void* d_ws, size_t ws_size,
                              hipStream_t stream)
{
    const float* nodes = (const float*)d_in[0];
    const int*   eidx  = (const int*)d_in[1];     // (2,E) int32
    const float* eattr = (const float*)d_in[2];
    const float* valid = (const float*)d_in[3];
    const float* W1 = (const float*)d_in[6];
    const float* b1 = (const float*)d_in[7];
    const float* W2 = (const float*)d_in[8];
    const float* b2 = (const float*)d_in[9];
    const float* Wg = (const float*)d_in[10];
    const float* bg = (const float*)d_in[11];
    const float* Ww = (const float*)d_in[12];
    const float* bw = (const float*)d_in[13];
    const float* Wf = (const float*)d_in[14];
    const float* bf = (const float*)d_in[15];
    const int* src = eidx;
    const int* dst = eidx + NE;
    char* ws = (char*)d_ws;
    float* out = (float*)d_out;

    size_t off = 0;
    auto carve = [&](size_t bytes) -> char* {
        char* p = ws + off;
        off += (bytes + 255) & ~(size_t)255;
        return p;
    };
    int*      ctrl = (int*)carve(4096);       // [0]=|E3| [1]=|E2| [2]=|E1| [3]=nloc
    unsigned* A = (unsigned*)carve(MASKW * 4);   // level-1 new nodes ({0} ∪ src(E3))
    unsigned* B = (unsigned*)carve(MASKW * 4);   // level-2 new nodes
    unsigned* C = (unsigned*)carve(MASKW * 4);   // level-3 new nodes (dedupe only)
    size_t zbytes = off;                         // memset region: ctrl + masks
    int*   n2l = (int*)carve((size_t)NN * 4);
    int*   l2n = (int*)carve((size_t)MAXLOC * 4);
    int4*  lists = (int4*)carve((size_t)3 * CAP_E * 16); // slot0=E3, slot1=E2, slot2=E1
    float* XA = (float*)carve((size_t)MAXLOC * LF * 4);
    float* XB = (float*)carve((size_t)MAXLOC * LF * 4);
    float* V1 = (float*)carve((size_t)MAXLOC * LF * 4);
    float* V2 = (float*)carve((size_t)MAXLOC * LF * 4);
    float* MV1 = (float*)carve((size_t)MAXLOC * 4);
    float* MV2 = (float*)carve((size_t)MAXLOC * 4);
    float* agg = (float*)carve((size_t)MAXLOC * LF * 4);
    if (off > ws_size) return;   // ~13 MB needed

    hipMemsetAsync(ws, 0, zbytes, stream);

    // BFS levels 1..3 (dst-sets {0}, A, A|B). agg zeroed piggyback on level 1.
    bfs_kernel<<<1024, 256, 0, stream>>>(src, dst, nullptr, nullptr, A,
                                         lists + 0 * CAP_E, ctrl + 0, ctrl + 3,
                                         n2l, l2n, agg, MAXLOC * LF);
    bfs_kernel<<<1024, 256, 0, stream>>>(src, dst, A, nullptr, B,
                                         lists + 1 * CAP_E, ctrl + 1, ctrl + 3,
                                         n2l, l2n, nullptr, 0);
    bfs_kernel<<<1024, 256, 0, stream>>>(src, dst, A, B, C,
                                         lists + 2 * CAP_E, ctrl + 2, ctrl + 3,
                                         n2l, l2n, nullptr, 0);
    // iteration 1: inline x0/v0 -> XA/V1/MV1, edges E1 (slot 2)
    iter_kernel<<<256, 256, 0, stream>>>(nodes, valid, eattr,
                                         W1, b1, W2, b2, Wg, bg, Ww, bw, Wf, bf,
                                         lists + 2 * CAP_E, ctrl + 2, ctrl + 3,
                                         n2l, l2n,
                                         nullptr, nullptr, nullptr,
                                         XA, V1, MV1, agg);
    // iteration 2: XA/V1/MV1 -> XB/V2/MV2, edges E2 (slot 1)
    iter_kernel<<<256, 256, 0, stream>>>(nodes, valid, eattr,
                                         W1, b1, W2, b2, Wg, bg, Ww, bw, Wf, bf,
                                         lists + 1 * CAP_E, ctrl + 1, ctrl + 3,
                                         n2l, l2n,
                                         XA, V1, MV1,
                                         XB, V2, MV2, agg);
    // iteration 3: node 0 only, edges E3 (slot 0)
    final_kernel<<<1, 256, 0, stream>>>(eattr,
                                        W1, b1, W2, b2, Wg, bg, Ww, bw, Wf, bf,
                                        lists + 0 * CAP_E, ctrl + 0,
                                        n2l, XB, V2, MV2, out);
}

// Round 5
// 395.427 us; speedup vs baseline: 2.4440x; 2.4440x over previous
//
#include <hip/hip_runtime.h>
#include <math.h>

// Problem constants (from reference)
#define NN 100000          // nodes
#define LF 48              // features per node
#define NE 1600000         // edges
#define EDIMS 17           // edge_attr dim
#define MASKW 3125         // NN/32 bitmask words
#define CAP_E 16384        // per-level edge-list capacity (expected ~5k max)
#define MAXLOC 12288       // active-node capacity (expected ~4.9k)
#define NWAVE_IT 1024      // iter/w0 kernels: 256 blocks x 4 waves; ownership modulus

static_assert((CAP_E & (CAP_E - 1)) == 0, "CAP_E pow2");
static_assert((NWAVE_IT & (NWAVE_IT - 1)) == 0, "NWAVE_IT pow2");

__device__ __forceinline__ float gelu_f(float x) {
    // jax.nn.gelu(approximate=False)
    return 0.5f * x * (1.0f + erff(x * 0.7071067811865475f));
}
__device__ __forceinline__ float sigm_f(float x) {
    return 1.0f / (1.0f + expf(-x));
}

// One BFS level. dst test: d in (MinA|MinB) (or d==0 when MinA==null).
// Selected edges recorded as (src_global, dloc, e, 0). New src nodes first-touch
// a loc via dedupe on Mout (Mout holds only THIS level's new nodes).
__global__ void __launch_bounds__(256) bfs_kernel(
    const int* __restrict__ src, const int* __restrict__ dst,
    const unsigned* __restrict__ MinA, const unsigned* __restrict__ MinB,
    unsigned* __restrict__ Mout, int4* __restrict__ list,
    int* __restrict__ cnt_e, int* __restrict__ cnt_loc,
    int* __restrict__ n2l, int* __restrict__ l2n,
    float* __restrict__ aggz, int aggn)
{
    const int tid = blockIdx.x * 256 + threadIdx.x;
    const int nt = gridDim.x * 256;
    if (aggz) for (int i = tid; i < aggn; i += nt) aggz[i] = 0.f;
    if (!MinA && tid == 0) {
        // seed node 0 (dedupes with any src==0 first-touch via atomicOr)
        unsigned old = atomicOr(&Mout[0], 1u);
        if (!(old & 1u)) {
            int loc = atomicAdd(cnt_loc, 1);
            if (loc < MAXLOC) { n2l[0] = loc; l2n[loc] = 0; }
        }
    }
    const int4* dst4 = (const int4*)dst;
    for (int e4 = tid; e4 < NE / 4; e4 += nt) {
        int4 d4 = dst4[e4];
        int ds_[4] = { d4.x, d4.y, d4.z, d4.w };
        #pragma unroll
        for (int q = 0; q < 4; ++q) {
            int d = ds_[q];
            bool hit;
            if (MinA) {
                unsigned m = MinA[d >> 5];
                if (MinB) m |= MinB[d >> 5];
                hit = (m >> (d & 31)) & 1u;
            } else {
                hit = (d == 0);
            }
            if (hit) {
                int e = e4 * 4 + q;
                int s = src[e];
                int idx = atomicAdd(cnt_e, 1);
                int dloc = MinA ? n2l[d] : 0;   // stable: d assigned in a prior kernel
                if (idx < CAP_E) list[idx] = make_int4(s, dloc, e, 0);
                unsigned sb = 1u << (s & 31);
                unsigned as = 0;
                if (MinA) { as = MinA[s >> 5]; if (MinB) as |= MinB[s >> 5]; }
                if (!(as & sb)) {               // s not assigned in prior levels
                    unsigned old = atomicOr(&Mout[s >> 5], sb);
                    if (!(old & sb)) {          // first touch this level
                        int loc = atomicAdd(cnt_loc, 1);
                        if (loc < MAXLOC) { n2l[s] = loc; l2n[loc] = s; }
                    }
                }
            }
        }
    }
}

// Precompute pass (one dispatch, 256 blocks x 256 thr):
//  (a) stage all MLP weights into LDS (22.5 KB) — kills 200-cyc global latency
//      on the MLP's dependent chain;
//  (b) wave-per-loc compact node init: X0c = nodes*valid, V0c = valid, MV0c;
//  (c) wave-per-edge: w0 = gelu(relu(gelu(ea@W1+b1)@W2+b2)@Wg+bg)@Ww + bw,
//      remap src -> sloc; entry rewritten to (sloc, dloc, w0bits, 0).
__global__ void __launch_bounds__(256) w0_kernel(
    const float* __restrict__ nodes, const float* __restrict__ valid,
    const float* __restrict__ eattr,
    const float* __restrict__ W1, const float* __restrict__ b1,
    const float* __restrict__ W2, const float* __restrict__ b2,
    const float* __restrict__ Wg, const float* __restrict__ bg,
    const float* __restrict__ Ww, const float* __restrict__ bw,
    int4* __restrict__ lists, const int* __restrict__ cnt,
    const int* __restrict__ cnt_loc_p,
    const int* __restrict__ n2l, const int* __restrict__ l2n,
    float* __restrict__ X0c, float* __restrict__ V0c, float* __restrict__ MV0c)
{
    __shared__ float sW1[EDIMS * 48];
    __shared__ float sW2[48 * 48];
    __shared__ float sWg[48 * 48];
    __shared__ float sb1[48], sb2[48], sbg[48], sWw[48];
    for (int i = threadIdx.x; i < EDIMS * 48; i += 256) sW1[i] = W1[i];
    for (int i = threadIdx.x; i < 48 * 48; i += 256) { sW2[i] = W2[i]; sWg[i] = Wg[i]; }
    if (threadIdx.x < 48) {
        sb1[threadIdx.x] = b1[threadIdx.x];
        sb2[threadIdx.x] = b2[threadIdx.x];
        sbg[threadIdx.x] = bg[threadIdx.x];
        sWw[threadIdx.x] = Ww[threadIdx.x];
    }
    __syncthreads();

    const int wid  = (blockIdx.x * 256 + threadIdx.x) >> 6;
    const int lane = threadIdx.x & 63;
    const float bwc = bw[0];

    // (b) compact node init
    int nloc = *cnt_loc_p; if (nloc > MAXLOC) nloc = MAXLOC;
    for (int loc = wid; loc < nloc; loc += NWAVE_IT) {
        int node = l2n[loc];
        float v = 0.f;
        if (lane < LF) {
            v = valid[(long)node * LF + lane];
            X0c[loc * LF + lane] = nodes[(long)node * LF + lane] * v;
            V0c[loc * LF + lane] = v;
        }
        float sv = v;
        #pragma unroll
        for (int o = 32; o > 0; o >>= 1) sv += __shfl_down(sv, o, 64);
        if (lane == 0) MV0c[loc] = sv * (1.0f / 48.0f);
    }

    // (c) wave-per-edge w0 (all three slots)
    for (int g = wid; g < 3 * CAP_E; g += NWAVE_IT) {
        int slot = g >> 14;
        int i = g & (CAP_E - 1);
        int c = cnt[slot]; if (c > CAP_E) c = CAP_E;
        if (i >= c) continue;
        int4 ent = lists[g];                          // (src_global, dloc, e, 0)
        const float* ea = eattr + (long)ent.z * EDIMS;
        float ea_l = (lane < EDIMS) ? ea[lane] : 0.f;
        float acc1 = (lane < 48) ? sb1[lane] : 0.f;
        #pragma unroll
        for (int k = 0; k < EDIMS; ++k) {
            float eak = __shfl(ea_l, k, 64);
            if (lane < 48) acc1 += eak * sW1[k * 48 + lane];
        }
        float h1 = (lane < 48) ? gelu_f(acc1) : 0.f;
        float acc2 = (lane < 48) ? sb2[lane] : 0.f;
        #pragma unroll
        for (int k = 0; k < 48; ++k) {
            float hk = __shfl(h1, k, 64);
            if (lane < 48) acc2 += hk * sW2[k * 48 + lane];
        }
        float h2 = fmaxf(acc2, 0.f);
        float acc3 = (lane < 48) ? sbg[lane] : 0.f;
        #pragma unroll
        for (int k = 0; k < 48; ++k) {
            float hk = __shfl(h2, k, 64);
            if (lane < 48) acc3 += hk * sWg[k * 48 + lane];
        }
        float part = (lane < 48) ? gelu_f(acc3) * sWw[lane] : 0.f;
        #pragma unroll
        for (int o = 32; o > 0; o >>= 1) part += __shfl_down(part, o, 64);
        if (lane == 0) {
            float w0 = part + bwc;
            int sl = n2l[ent.x]; if ((unsigned)sl >= (unsigned)MAXLOC) sl = 0;
            lists[g] = make_int4(sl, ent.y, __float_as_int(w0), 0);
        }
    }
}

// One message-passing iteration: dst-ownership scatter (wave = dloc mod NWAVE_IT,
// exclusive non-atomic accumulate into agg) immediately followed by update of the
// wave's own locs — no sync needed. w0/sloc are precomputed; per-edge body is
// one scalar load + sigmoid + 48-lane FMA.
__global__ void __launch_bounds__(256) iter_kernel(
    const float* __restrict__ Wf, const float* __restrict__ bf,
    const int4* __restrict__ list, const int* __restrict__ cnt_e_p,
    const int* __restrict__ cnt_loc_p,
    const float* __restrict__ X0c,
    const float* __restrict__ Xprev, const float* __restrict__ Vprev,
    const float* __restrict__ MVprev,
    float* __restrict__ Xc, float* __restrict__ Vc, float* __restrict__ MVc,
    float* __restrict__ agg)
{
    const int wid  = (blockIdx.x * 256 + threadIdx.x) >> 6;
    const int lane = threadIdx.x & 63;
    int c = *cnt_e_p;      if (c > CAP_E) c = CAP_E;
    int nloc = *cnt_loc_p; if (nloc > MAXLOC) nloc = MAXLOC;

    // ---- scatter: scan list in coalesced 64-entry chunks, extract owned edges ----
    for (int base = 0; base < c; base += 64) {
        int4 ent = make_int4(0, 0, 0, 0);
        bool own = false;
        int j = base + lane;
        if (j < c) {
            ent = list[j];
            own = ((unsigned)ent.y < (unsigned)MAXLOC) &&
                  ((ent.y & (NWAVE_IT - 1)) == wid);
        }
        unsigned long long sel = __ballot(own);
        while (sel) {
            int b = __ffsll(sel) - 1;
            sel &= sel - 1;
            int sloc = __shfl(ent.x, b, 64);
            int dloc = __shfl(ent.y, b, 64);
            float w0 = __shfl(__int_as_float(ent.z), b, 64);
            float sg = sigm_f(MVprev[sloc] * w0);
            if (lane < LF) agg[dloc * LF + lane] += sg * Xprev[sloc * LF + lane];
        }
    }

    // ---- update this wave's locs (ownership loc ≡ wid mod NWAVE_IT); re-zero agg ----
    const float wf0 = Wf[0], wf1 = Wf[1], wf2 = Wf[2], bfc = bf[0];
    for (int loc = wid; loc < nloc; loc += NWAVE_IT) {
        float vn = 0.f;
        if (lane < LF) {
            float nh = agg[loc * LF + lane];
            agg[loc * LF + lane] = 0.f;
            float x0v = X0c[loc * LF + lane];
            float xo = Xprev[loc * LF + lane];
            float vp = Vprev[loc * LF + lane];
            float nv = 1.0f - vp;
            float m  = sigm_f(nh * wf0 + xo * wf1 + nv * wf2 + bfc);
            float xn = (1.0f - m) * xo + nv * m * nh;
            vn = ((x0v != xn) || (vp > 0.f)) ? 1.0f : 0.0f;
            if (lane == 0) vn = 0.0f;
            Xc[loc * LF + lane] = xn;
            Vc[loc * LF + lane] = vn;
        }
        float sv = vn;
        #pragma unroll
        for (int o = 32; o > 0; o >>= 1) sv += __shfl_down(sv, o, 64);
        if (lane == 0) MVc[loc] = sv * (1.0f / 48.0f);
    }
}

// Final iteration: only node 0 is updated/output. One block; 4 waves split the
// E3 list (w0 precomputed), partials reduced through LDS, wave 0 writes out.
__global__ void __launch_bounds__(256) final_kernel(
    const float* __restrict__ Wf, const float* __restrict__ bf,
    const int4* __restrict__ list, const int* __restrict__ cnt_e_p,
    const int* __restrict__ n2l,
    const float* __restrict__ Xprev, const float* __restrict__ Vprev,
    const float* __restrict__ MVprev, float* __restrict__ out)
{
    __shared__ float part[4][LF];
    const int w = threadIdx.x >> 6;
    const int lane = threadIdx.x & 63;
    int c = *cnt_e_p; if (c > CAP_E) c = CAP_E;
    float acc = 0.f;
    for (int j = w; j < c; j += 4) {
        int4 ent = list[j];                           // (sloc, dloc=loc0, w0bits, 0)
        float sg = sigm_f(MVprev[ent.x] * __int_as_float(ent.z));
        if (lane < LF) acc += sg * Xprev[ent.x * LF + lane];
    }
    if (lane < LF) part[w][lane] = acc;
    __syncthreads();
    if (w == 0 && lane < LF) {
        float nh = part[0][lane] + part[1][lane] + part[2][lane] + part[3][lane];
        int loc0 = n2l[0]; if ((unsigned)loc0 >= (unsigned)MAXLOC) loc0 = 0;
        float xo = Xprev[loc0 * LF + lane];
        float vp = Vprev[loc0 * LF + lane];
        float nv = 1.0f - vp;
        float m  = sigm_f(nh * Wf[0] + xo * Wf[1] + nv * Wf[2] + bf[0]);
        out[lane] = (1.0f - m) * xo + nv * m * nh;
    }
}

extern "C" void kernel_launch(void* const* d_in, const int* in_sizes, int n_in,
                              void* d_out, int out_size, void* d_ws, size_t ws_size,
                              hipStream_t stream)
{
    const float* nodes = (const float*)d_in[0];
    const int*   eidx  = (const int*)d_in[1];     // (2,E) int32
    const float* eattr = (const float*)d_in[2];
    const float* valid = (const float*)d_in[3];
    const float* W1 = (const float*)d_in[6];
    const float* b1 = (const float*)d_in[7];
    const float* W2 = (const float*)d_in[8];
    const float* b2 = (const float*)d_in[9];
    const float* Wg = (const float*)d_in[10];
    const float* bg = (const float*)d_in[11];
    const float* Ww = (const float*)d_in[12];
    const float* bw = (const float*)d_in[13];
    const float* Wf = (const float*)d_in[14];
    const float* bf = (const float*)d_in[15];
    const int* src = eidx;
    const int* dst = eidx + NE;
    char* ws = (char*)d_ws;
    float* out = (float*)d_out;

    size_t off = 0;
    auto carve = [&](size_t bytes) -> char* {
        char* p = ws + off;
        off += (bytes + 255) & ~(size_t)255;
        return p;
    };
    int*      ctrl = (int*)carve(4096);          // [0]=|E3| [1]=|E2| [2]=|E1| [3]=nloc
    unsigned* A = (unsigned*)carve(MASKW * 4);   // level-1 new nodes ({0} ∪ src(E3))
    unsigned* B = (unsigned*)carve(MASKW * 4);   // level-2 new nodes
    unsigned* C = (unsigned*)carve(MASKW * 4);   // level-3 new nodes (dedupe only)
    size_t zbytes = off;                         // memset region: ctrl + masks
    int*   n2l = (int*)carve((size_t)NN * 4);
    int*   l2n = (int*)carve((size_t)MAXLOC * 4);
    int4*  lists = (int4*)carve((size_t)3 * CAP_E * 16); // slot0=E3, slot1=E2, slot2=E1
    float* X0c = (float*)carve((size_t)MAXLOC * LF * 4);
    float* V0c = (float*)carve((size_t)MAXLOC * LF * 4);
    float* XA  = (float*)carve((size_t)MAXLOC * LF * 4);
    float* XB  = (float*)carve((size_t)MAXLOC * LF * 4);
    float* V1  = (float*)carve((size_t)MAXLOC * LF * 4);
    float* V2  = (float*)carve((size_t)MAXLOC * LF * 4);
    float* MV0 = (float*)carve((size_t)MAXLOC * 4);
    float* MV1 = (float*)carve((size_t)MAXLOC * 4);
    float* MV2 = (float*)carve((size_t)MAXLOC * 4);
    float* agg = (float*)carve((size_t)MAXLOC * LF * 4);
    if (off > ws_size) return;   // ~18 MB needed

    hipMemsetAsync(ws, 0, zbytes, stream);

    // BFS levels 1..3 (dst-sets {0}, A, A|B). agg zeroed piggyback on level 1.
    bfs_kernel<<<1024, 256, 0, stream>>>(src, dst, nullptr, nullptr, A,
                                         lists + 0 * CAP_E, ctrl + 0, ctrl + 3,
                                         n2l, l2n, agg, MAXLOC * LF);
    bfs_kernel<<<1024, 256, 0, stream>>>(src, dst, A, nullptr, B,
                                         lists + 1 * CAP_E, ctrl + 1, ctrl + 3,
                                         n2l, l2n, nullptr, 0);
    bfs_kernel<<<1024, 256, 0, stream>>>(src, dst, A, B, C,
                                         lists + 2 * CAP_E, ctrl + 2, ctrl + 3,
                                         n2l, l2n, nullptr, 0);
    // precompute: node init (X0c/V0c/MV0) + per-edge w0 + src remap
    w0_kernel<<<256, 256, 0, stream>>>(nodes, valid, eattr,
                                       W1, b1, W2, b2, Wg, bg, Ww, bw,
                                       lists, ctrl, ctrl + 3, n2l, l2n,
                                       X0c, V0c, MV0);
    // iteration 1: X0c/V0c/MV0 -> XA/V1/MV1, edges E1 (slot 2)
    iter_kernel<<<256, 256, 0, stream>>>(Wf, bf,
                                         lists + 2 * CAP_E, ctrl + 2, ctrl + 3,
                                         X0c, X0c, V0c, MV0,
                                         XA, V1, MV1, agg);
    // iteration 2: XA/V1/MV1 -> XB/V2/MV2, edges E2 (slot 1)
    iter_kernel<<<256, 256, 0, stream>>>(Wf, bf,
                                         lists + 1 * CAP_E, ctrl + 1, ctrl + 3,
                                         X0c, XA, V1, MV1,
                                         XB, V2, MV2, agg);
    // iteration 3: node 0 only, edges E3 (slot 0)
    final_kernel<<<1, 256, 0, stream>>>(Wf, bf,
                                        lists + 0 * CAP_E, ctrl + 0,
                                        n2l, XB, V2, MV2, out);
}